// Round 1
// 1383.928 us; speedup vs baseline: 1.0580x; 1.0580x over previous
//
#include <hip/hip_runtime.h>
#include <hip/hip_bf16.h>
#include <cstdint>
#include <cstddef>

using bf16x8 = __attribute__((ext_vector_type(8))) __bf16;
using f32x4  = __attribute__((ext_vector_type(4))) float;

__device__ __forceinline__ unsigned short f2bf(float f) {
  unsigned int u = __float_as_uint(f);
  u += 0x7FFFu + ((u >> 16) & 1u);   // RNE
  return (unsigned short)(u >> 16);
}

__device__ __forceinline__ void async_cp16(const void* g, void* l) {
  __builtin_amdgcn_global_load_lds(
      (const __attribute__((address_space(1))) unsigned int*)g,
      (__attribute__((address_space(3))) unsigned int*)l, 16, 0, 0);
}

// ---------------- weight fp32 -> bf16 transpose: W[K,N] -> Wt[N,K] ----------------
__global__ __launch_bounds__(256) void wconv(const float* __restrict__ W,
                                             unsigned short* __restrict__ Wt,
                                             int K, int N) {
  __shared__ float tile[32][33];
  const int n0 = blockIdx.x * 32;
  const int k0 = blockIdx.y * 32;
  const int tx = threadIdx.x;   // 0..31
  const int ty = threadIdx.y;   // 0..7
  for (int i = 0; i < 32; i += 8)
    tile[ty + i][tx] = W[(size_t)(k0 + ty + i) * N + n0 + tx];
  __syncthreads();
  for (int i = 0; i < 32; i += 8)
    Wt[(size_t)(n0 + ty + i) * K + k0 + tx] = f2bf(tile[tx][ty + i]);
}

// ---------------- score softmax + reweight: one block per row ----------------
__global__ __launch_bounds__(256) void score_kernel(
    const float* __restrict__ ft0, const float* __restrict__ ft1,
    const float* __restrict__ ft2, const float* __restrict__ key,
    float* __restrict__ out_f, unsigned short* __restrict__ out_b) {
  const int row  = blockIdx.x;
  const int t    = threadIdx.x;
  const int lane = t & 63;
  const int w    = t >> 6;    // wave 0..3
  const int h    = t >> 7;    // half 0..1
  __shared__ float wsum[6][4];
  __shared__ float mult[12];

  const float4* k4 = (const float4*)key;
  float4 v[6];
#pragma unroll
  for (int i = 0; i < 6; i++) {
    const int idx4 = t + 256 * i;          // float4 index in row (0..1535)
    const int e    = idx4 * 4;             // element index in row
    const float* tsrc = (i < 2) ? ft0 : (i < 4) ? ft1 : ft2;  // tensor = i>>1 (compile-time)
    v[i] = *(const float4*)(tsrc + (size_t)row * 2048 + (e & 2047));
    float4 kv = k4[idx4 & 127];
    float p = v[i].x * kv.x + v[i].y * kv.y + v[i].z * kv.z + v[i].w * kv.w;
#pragma unroll
    for (int o = 32; o > 0; o >>= 1) p += __shfl_down(p, o, 64);
    if (lane == 0) wsum[i][w] = p;         // chunk for this wave = 2*i + h
  }
  __syncthreads();
  if (t == 0) {
    float s[12];
    float mx = -1e30f;
    for (int c = 0; c < 12; c++) {
      s[c] = wsum[c >> 1][2 * (c & 1)] + wsum[c >> 1][2 * (c & 1) + 1];
      mx = fmaxf(mx, s[c]);
    }
    float tot = 0.f;
    for (int c = 0; c < 12; c++) { s[c] = expf(s[c] - mx); tot += s[c]; }
    const float inv = 1.0f / tot;
    for (int c = 0; c < 12; c++) mult[c] = 1.0f + s[c] * inv;
  }
  __syncthreads();
#pragma unroll
  for (int i = 0; i < 6; i++) {
    const int idx4 = t + 256 * i;
    const int e    = idx4 * 4;
    const float m  = mult[2 * i + h];
    float4 o;
    o.x = v[i].x * m; o.y = v[i].y * m; o.z = v[i].z * m; o.w = v[i].w * m;
    *(float4*)(out_f + (size_t)row * 6144 + e) = o;
    ushort4 ob;
    ob.x = f2bf(o.x); ob.y = f2bf(o.y); ob.z = f2bf(o.z); ob.w = f2bf(o.w);
    *(ushort4*)(out_b + (size_t)row * 6144 + e) = ob;
  }
}

// ---------------- 256x256-tile bf16 MFMA GEMM, BK=32, ring-4 LDS, counted vmcnt ----------------
// C = A[M,K] * Bt[N,K]^T + bias.  EPI 0: C fp32.  EPI 1: relu, C fp32 + optional bf16 copy.
// 8 waves (2M x 4N), per-wave 128x64 output. LDS 128 KiB = 4 slots x (A 16K + B 16K).
// Swizzle: involution  off ^= ((off>>7)&7)<<4  applied to BOTH the pre-swizzled global
// source of global_load_lds (LDS dest linear) and the ds_read_b128 fragment address.
// Sync: raw s_barrier + counted s_waitcnt vmcnt(12) (prefetch distance 3 tiles) -- never
// drains to 0 in steady state. Slot (kt+3)&3 == (kt-1)&3 is only written after the
// trailing barrier of iteration kt-1, which all waves pass only after consuming it.
template <int EPI>
__global__ __launch_bounds__(512, 2) void gemm256(
    const unsigned short* __restrict__ A,   // bf16 [M,K] row-major
    const unsigned short* __restrict__ Bt,  // bf16 [N,K] row-major
    const float* __restrict__ bias,         // [N]
    float* __restrict__ C,                  // [M,N]
    unsigned short* __restrict__ Cbf,       // [M,N] bf16 or nullptr
    int M, int N, int K) {
  __shared__ __align__(16) unsigned short smem[65536];   // 131072 B
  const int t    = threadIdx.x;
  const int lane = t & 63;
  const int w    = t >> 6;          // 0..7
  const int wm   = w >> 2;          // 0..1
  const int wn   = w & 3;           // 0..3
  const int frow = lane & 15;
  const int quad = lane >> 4;
  const size_t m0 = (size_t)blockIdx.y * 256;
  const size_t n0 = (size_t)blockIdx.x * 256;

  // ---- staging: waves 0-3 stage A rows [seg..seg+64), waves 4-7 same for B ----
  const bool isB  = w >= 4;
  const int  seg  = (w & 3) * 4096;             // byte offset within 16KB region
  const int  off0 = seg + lane * 16;            // linear LDS offset this lane writes (call 0)
  const int  pos0 = off0 ^ (((off0 >> 7) & 7) << 4);   // logical position (involution)
  const int  r0   = pos0 >> 6;                  // logical row 0..255 (call i adds 16)
  const int  kb0  = pos0 & 63;                  // k-byte 0..63
  const unsigned short* gp =
      (isB ? Bt + (n0 + (size_t)r0) * K : A + (m0 + (size_t)r0) * K) + (kb0 >> 1);
  char* lseg = (char*)smem + (isB ? 16384 : 0) + seg;   // wave-uniform LDS base

  // ---- swizzled fragment-read byte offsets (constant across mi/ni: +1024 each) ----
  const int offA = (wm * 128 + frow) * 64 + quad * 16;
  const int aoff = offA ^ (((offA >> 7) & 7) << 4);
  const int offB = (wn * 64 + frow) * 64 + quad * 16;
  const int boff = 16384 + (offB ^ (((offB >> 7) & 7) << 4));

  f32x4 acc[8][4];
  const f32x4 z = {0.f, 0.f, 0.f, 0.f};
#pragma unroll
  for (int i = 0; i < 8; i++)
#pragma unroll
    for (int j = 0; j < 4; j++) acc[i][j] = z;

  const int nkt = K >> 5;   // K / 32, always >= 4 here

  auto stage = [&](int slot) {               // one K-tile: 4 x 1KB per wave
    char* lb = lseg + slot * 32768;
    async_cp16(gp,                  lb);
    async_cp16(gp + (size_t)16 * K, lb + 1024);
    async_cp16(gp + (size_t)32 * K, lb + 2048);
    async_cp16(gp + (size_t)48 * K, lb + 3072);
    gp += 32;                                // advance one K-tile
  };

  auto compute = [&](int slot) {
    const char* base = (const char*)smem + slot * 32768;
    bf16x8 af[8], bv[4];
#pragma unroll
    for (int mi = 0; mi < 8; ++mi)
      af[mi] = *(const bf16x8*)(base + aoff + mi * 1024);
#pragma unroll
    for (int ni = 0; ni < 4; ++ni)
      bv[ni] = *(const bf16x8*)(base + boff + ni * 1024);
    __builtin_amdgcn_s_setprio(1);
#pragma unroll
    for (int mi = 0; mi < 8; ++mi)
#pragma unroll
      for (int ni = 0; ni < 4; ++ni)
        acc[mi][ni] = __builtin_amdgcn_mfma_f32_16x16x32_bf16(af[mi], bv[ni], acc[mi][ni], 0, 0, 0);
    __builtin_amdgcn_s_setprio(0);
  };

  // prologue: 3 tiles in flight (12 loads/wave)
  stage(0); stage(1); stage(2);
  int kt = 0;
  for (; kt + 3 < nkt; ++kt) {
    stage((kt + 3) & 3);                               // 16 outstanding
    asm volatile("s_waitcnt vmcnt(12)" ::: "memory");  // tile kt landed (issued 3 iters ago)
    asm volatile("s_barrier" ::: "memory");            // all waves' pieces visible
    compute(kt & 3);
    asm volatile("s_waitcnt lgkmcnt(0)\n\ts_barrier" ::: "memory");  // reads done before overwrite
  }
  // epilogue: drain 8 -> 4 -> 0 (no further stages, no trailing barriers needed)
  asm volatile("s_waitcnt vmcnt(8)" ::: "memory");
  asm volatile("s_barrier" ::: "memory");
  compute(kt & 3); ++kt;
  asm volatile("s_waitcnt vmcnt(4)" ::: "memory");
  asm volatile("s_barrier" ::: "memory");
  compute(kt & 3); ++kt;
  asm volatile("s_waitcnt vmcnt(0)" ::: "memory");
  asm volatile("s_barrier" ::: "memory");
  compute(kt & 3);

  // ---- epilogue: C mapping col = lane&15, row = quad*4 + reg (verified layout) ----
#pragma unroll
  for (int mi = 0; mi < 8; ++mi) {
    const size_t rowb = m0 + wm * 128 + mi * 16 + quad * 4;
#pragma unroll
    for (int ni = 0; ni < 4; ++ni) {
      const size_t col = n0 + wn * 64 + ni * 16 + frow;
      const float bvs = bias[col];
#pragma unroll
      for (int r = 0; r < 4; ++r) {
        float v = acc[mi][ni][r] + bvs;
        if (EPI == 1) v = fmaxf(v, 0.f);
        const size_t idx = (rowb + r) * (size_t)N + col;
        C[idx] = v;
        if (EPI == 1 && Cbf != nullptr) Cbf[idx] = f2bf(v);
      }
    }
  }
}

// ---------------- BatchNorm: partial column sums -> finalize -> normalize(bf16) ----------------
__global__ __launch_bounds__(256) void bn_accum(const float* __restrict__ h,
                                                float* __restrict__ ps,
                                                float* __restrict__ pq, int N) {
  const int c  = blockIdx.x * 256 + threadIdx.x;
  const int r0 = blockIdx.y * 256;
  const float* p = h + (size_t)r0 * N + c;
  float s = 0.f, q = 0.f;
  for (int r = 0; r < 256; r++) {
    float x = p[(size_t)r * N];
    s += x; q += x * x;
  }
  ps[(size_t)blockIdx.y * N + c] = s;
  pq[(size_t)blockIdx.y * N + c] = q;
}

__global__ __launch_bounds__(256) void bn_final(const float* __restrict__ ps,
                                                const float* __restrict__ pq,
                                                const float* __restrict__ g,
                                                const float* __restrict__ beta,
                                                float* __restrict__ stats,
                                                int N, int nb, float invM) {
  const int c = blockIdx.x * 256 + threadIdx.x;
  float s = 0.f, q = 0.f;
  for (int b = 0; b < nb; b++) { s += ps[(size_t)b * N + c]; q += pq[(size_t)b * N + c]; }
  const float mean = s * invM;
  const float var  = q * invM - mean * mean;
  const float sc   = g[c] * rsqrtf(var + 1e-5f);
  stats[c]     = sc;
  stats[N + c] = beta[c] - mean * sc;
}

__global__ __launch_bounds__(256) void bn_norm(const float* __restrict__ h,
                                               const float* __restrict__ stats,
                                               unsigned short* __restrict__ hb, int N) {
  const size_t i4 = (size_t)blockIdx.x * 256 + threadIdx.x;
  const float4 x = ((const float4*)h)[i4];
  const int c = (int)((i4 * 4) & (size_t)(N - 1));   // N = 2048 (pow2)
  const float4 sc = *(const float4*)(stats + c);
  const float4 tt = *(const float4*)(stats + N + c);
  ushort4 ob;
  ob.x = f2bf(x.x * sc.x + tt.x);
  ob.y = f2bf(x.y * sc.y + tt.y);
  ob.z = f2bf(x.z * sc.z + tt.z);
  ob.w = f2bf(x.w * sc.w + tt.w);
  ((ushort4*)hb)[i4] = ob;
}

// ---------------- launch ----------------
extern "C" void kernel_launch(void* const* d_in, const int* in_sizes, int n_in,
                              void* d_out, int out_size, void* d_ws, size_t ws_size,
                              hipStream_t stream) {
  const float* ft0 = (const float*)d_in[1];
  const float* ft1 = (const float*)d_in[2];
  const float* ft2 = (const float*)d_in[3];
  const float* key = (const float*)d_in[4];
  const float* W1  = (const float*)d_in[5];
  const float* b1  = (const float*)d_in[6];
  const float* g1  = (const float*)d_in[7];
  const float* be1 = (const float*)d_in[8];
  const float* W2  = (const float*)d_in[9];
  const float* b2  = (const float*)d_in[10];
  const float* g2  = (const float*)d_in[11];
  const float* be2 = (const float*)d_in[12];
  const float* W3  = (const float*)d_in[13];
  const float* b3  = (const float*)d_in[14];
  const float* We  = (const float*)d_in[15];
  const float* bE  = (const float*)d_in[16];

  float* out         = (float*)d_out;
  float* out_aligned = out;                                         // [8192,2048]
  float* out_extend  = out + (size_t)8192 * 2048;                   // [8192,6144]
  float* out_ft      = out + (size_t)8192 * 2048 + (size_t)8192 * 6144;  // [8192,6144]

  char* ws = (char*)d_ws;
  unsigned short* ft_bf = (unsigned short*)(ws);                 // 100,663,296 B
  unsigned short* Wt1   = (unsigned short*)(ws + 100663296ull);  //  25,165,824
  unsigned short* Wt2   = (unsigned short*)(ws + 125829120ull);  //   8,388,608
  unsigned short* Wt3   = (unsigned short*)(ws + 134217728ull);  //   8,388,608
  unsigned short* WtE   = (unsigned short*)(ws + 142606336ull);  //  25,165,824
  float*          hf    = (float*)(ws + 167772160ull);           //  67,108,864
  unsigned short* hba   = (unsigned short*)(ws + 234881024ull);  //  33,554,432
  unsigned short* hbb   = (unsigned short*)(ws + 268435456ull);  //  33,554,432
  float*          psum  = (float*)(ws + 301989888ull);           //     262,144
  float*          psq   = (float*)(ws + 302252032ull);           //     262,144
  float*          stats = (float*)(ws + 302514176ull);           //      16,384

  const dim3 blk32(32, 8);
  wconv<<<dim3(2048 / 32, 6144 / 32), blk32, 0, stream>>>(W1, Wt1, 6144, 2048);
  wconv<<<dim3(2048 / 32, 2048 / 32), blk32, 0, stream>>>(W2, Wt2, 2048, 2048);
  wconv<<<dim3(2048 / 32, 2048 / 32), blk32, 0, stream>>>(W3, Wt3, 2048, 2048);
  wconv<<<dim3(6144 / 32, 2048 / 32), blk32, 0, stream>>>(We, WtE, 2048, 6144);

  score_kernel<<<dim3(8192), dim3(256), 0, stream>>>(ft0, ft1, ft2, key, out_ft, ft_bf);

  // layer 1: h = ft_all @ W1 + b1 ; BN
  gemm256<0><<<dim3(8, 32), dim3(512), 0, stream>>>(ft_bf, Wt1, b1, hf,
                                                    (unsigned short*)nullptr, 8192, 2048, 6144);
  bn_accum<<<dim3(8, 32), dim3(256), 0, stream>>>(hf, psum, psq, 2048);
  bn_final<<<dim3(8), dim3(256), 0, stream>>>(psum, psq, g1, be1, stats, 2048, 32, 1.0f / 8192.0f);
  bn_norm<<<dim3(16384), dim3(256), 0, stream>>>(hf, stats, hba, 2048);

  // layer 2: h = h1n @ W2 + b2 ; BN
  gemm256<0><<<dim3(8, 32), dim3(512), 0, stream>>>(hba, Wt2, b2, hf,
                                                    (unsigned short*)nullptr, 8192, 2048, 2048);
  bn_accum<<<dim3(8, 32), dim3(256), 0, stream>>>(hf, psum, psq, 2048);
  bn_final<<<dim3(8), dim3(256), 0, stream>>>(psum, psq, g2, be2, stats, 2048, 32, 1.0f / 8192.0f);
  bn_norm<<<dim3(16384), dim3(256), 0, stream>>>(hf, stats, hba, 2048);

  // layer 3: aligned = relu(h2n @ W3 + b3)  -> fp32 out + bf16 copy
  gemm256<1><<<dim3(8, 32), dim3(512), 0, stream>>>(hba, Wt3, b3, out_aligned, hbb,
                                                    8192, 2048, 2048);
  // extend = relu(aligned @ We + bE)
  gemm256<1><<<dim3(24, 32), dim3(512), 0, stream>>>(hbb, WtE, bE, out_extend,
                                                     (unsigned short*)nullptr, 8192, 6144, 2048);
}

// Round 2
// 1332.922 us; speedup vs baseline: 1.0984x; 1.0383x over previous
//
#include <hip/hip_runtime.h>
#include <hip/hip_bf16.h>
#include <cstdint>
#include <cstddef>

using bf16x8 = __attribute__((ext_vector_type(8))) __bf16;
using f32x4  = __attribute__((ext_vector_type(4))) float;

__device__ __forceinline__ unsigned short f2bf(float f) {
  unsigned int u = __float_as_uint(f);
  u += 0x7FFFu + ((u >> 16) & 1u);   // RNE
  return (unsigned short)(u >> 16);
}

__device__ __forceinline__ void async_cp16(const void* g, void* l) {
  __builtin_amdgcn_global_load_lds(
      (const __attribute__((address_space(1))) unsigned int*)g,
      (__attribute__((address_space(3))) unsigned int*)l, 16, 0, 0);
}

// ---------------- weight fp32 -> bf16 transpose: W[K,N] -> Wt[N,K] ----------------
__global__ __launch_bounds__(256) void wconv(const float* __restrict__ W,
                                             unsigned short* __restrict__ Wt,
                                             int K, int N) {
  __shared__ float tile[32][33];
  const int n0 = blockIdx.x * 32;
  const int k0 = blockIdx.y * 32;
  const int tx = threadIdx.x;   // 0..31
  const int ty = threadIdx.y;   // 0..7
  for (int i = 0; i < 32; i += 8)
    tile[ty + i][tx] = W[(size_t)(k0 + ty + i) * N + n0 + tx];
  __syncthreads();
  for (int i = 0; i < 32; i += 8)
    Wt[(size_t)(n0 + ty + i) * K + k0 + tx] = f2bf(tile[tx][ty + i]);
}

// ---------------- score softmax + reweight: one block per row ----------------
__global__ __launch_bounds__(256) void score_kernel(
    const float* __restrict__ ft0, const float* __restrict__ ft1,
    const float* __restrict__ ft2, const float* __restrict__ key,
    float* __restrict__ out_f, unsigned short* __restrict__ out_b) {
  const int row  = blockIdx.x;
  const int t    = threadIdx.x;
  const int lane = t & 63;
  const int w    = t >> 6;    // wave 0..3
  const int h    = t >> 7;    // half 0..1
  __shared__ float wsum[6][4];
  __shared__ float mult[12];

  const float4* k4 = (const float4*)key;
  float4 v[6];
#pragma unroll
  for (int i = 0; i < 6; i++) {
    const int idx4 = t + 256 * i;          // float4 index in row (0..1535)
    const int e    = idx4 * 4;             // element index in row
    const float* tsrc = (i < 2) ? ft0 : (i < 4) ? ft1 : ft2;  // tensor = i>>1 (compile-time)
    v[i] = *(const float4*)(tsrc + (size_t)row * 2048 + (e & 2047));
    float4 kv = k4[idx4 & 127];
    float p = v[i].x * kv.x + v[i].y * kv.y + v[i].z * kv.z + v[i].w * kv.w;
#pragma unroll
    for (int o = 32; o > 0; o >>= 1) p += __shfl_down(p, o, 64);
    if (lane == 0) wsum[i][w] = p;         // chunk for this wave = 2*i + h
  }
  __syncthreads();
  if (t == 0) {
    float s[12];
    float mx = -1e30f;
    for (int c = 0; c < 12; c++) {
      s[c] = wsum[c >> 1][2 * (c & 1)] + wsum[c >> 1][2 * (c & 1) + 1];
      mx = fmaxf(mx, s[c]);
    }
    float tot = 0.f;
    for (int c = 0; c < 12; c++) { s[c] = expf(s[c] - mx); tot += s[c]; }
    const float inv = 1.0f / tot;
    for (int c = 0; c < 12; c++) mult[c] = 1.0f + s[c] * inv;
  }
  __syncthreads();
#pragma unroll
  for (int i = 0; i < 6; i++) {
    const int idx4 = t + 256 * i;
    const int e    = idx4 * 4;
    const float m  = mult[2 * i + h];
    float4 o;
    o.x = v[i].x * m; o.y = v[i].y * m; o.z = v[i].z * m; o.w = v[i].w * m;
    *(float4*)(out_f + (size_t)row * 6144 + e) = o;
    ushort4 ob;
    ob.x = f2bf(o.x); ob.y = f2bf(o.y); ob.z = f2bf(o.z); ob.w = f2bf(o.w);
    *(ushort4*)(out_b + (size_t)row * 6144 + e) = ob;
  }
}

// ---------------- 256x256-tile bf16 MFMA GEMM, BK=32, ring-4 LDS ----------------
// Software-pipelined fragment reads: ONE barrier per K-step.
// Invariant at iteration kt entry: tiles kt and kt+1 are landed AND published
// (trailing s_waitcnt vmcnt(4) + s_barrier of iteration kt-1 confirmed tile kt+1:
// at that point loads issued cover tiles <= kt+2, outstanding <= 8, wait 4 ->
// tiles <= kt+1 landed in every wave; barrier publishes).
// Iteration kt: stage(kt+3) | MFMA on frags of tile kt (read last iter, lgkm done)
//             | ds_read frags of tile kt+1 (slot valid per invariant; latency hides
//               under trailing wait + barrier + next stage) | vmcnt(4); s_barrier.
// Slot overwrite safety: stage at iter kt writes slot (kt+3)&3 = tile kt-1's slot;
// tile kt-1's ds_reads were consumed (compiler lgkm wait) before iter kt-1's
// trailing barrier, which all waves passed before this stage.
template <int EPI>
__global__ __launch_bounds__(512, 2) void gemm256(
    const unsigned short* __restrict__ A,   // bf16 [M,K] row-major
    const unsigned short* __restrict__ Bt,  // bf16 [N,K] row-major
    const float* __restrict__ bias,         // [N]
    float* __restrict__ C,                  // [M,N]
    unsigned short* __restrict__ Cbf,       // [M,N] bf16 or nullptr
    int M, int N, int K) {
  __shared__ __align__(16) unsigned short smem[65536];   // 131072 B
  const int t    = threadIdx.x;
  const int lane = t & 63;
  const int w    = t >> 6;          // 0..7
  const int wm   = w >> 2;          // 0..1
  const int wn   = w & 3;           // 0..3
  const int frow = lane & 15;
  const int quad = lane >> 4;
  const size_t m0 = (size_t)blockIdx.y * 256;
  const size_t n0 = (size_t)blockIdx.x * 256;

  // ---- staging: waves 0-3 stage A rows, waves 4-7 stage B rows ----
  const bool isB  = w >= 4;
  const int  seg  = (w & 3) * 4096;             // byte offset within 16KB region
  const int  off0 = seg + lane * 16;            // linear LDS offset this lane writes
  const int  pos0 = off0 ^ (((off0 >> 7) & 7) << 4);   // logical position (involution)
  const int  r0   = pos0 >> 6;                  // logical row 0..255
  const int  kb0  = pos0 & 63;                  // k-byte 0..63
  const unsigned short* gp =
      (isB ? Bt + (n0 + (size_t)r0) * K : A + (m0 + (size_t)r0) * K) + (kb0 >> 1);
  char* lseg = (char*)smem + (isB ? 16384 : 0) + seg;   // wave-uniform LDS base

  // ---- swizzled fragment-read byte offsets (+1024 per tile index is swizzle-safe) ----
  const int offA = (wm * 128 + frow) * 64 + quad * 16;
  const int aoff = offA ^ (((offA >> 7) & 7) << 4);
  const int offB = (wn * 64 + frow) * 64 + quad * 16;
  const int boff = 16384 + (offB ^ (((offB >> 7) & 7) << 4));

  f32x4 acc[8][4];
  const f32x4 z = {0.f, 0.f, 0.f, 0.f};
#pragma unroll
  for (int i = 0; i < 8; i++)
#pragma unroll
    for (int j = 0; j < 4; j++) acc[i][j] = z;

  const int nkt = K >> 5;   // K / 32 (64 or 192 here; even, >= 8)

  auto stage = [&](int slot) {               // one K-tile: 4 x 1KB per wave
    char* lb = lseg + slot * 32768;
    async_cp16(gp,                  lb);
    async_cp16(gp + (size_t)16 * K, lb + 1024);
    async_cp16(gp + (size_t)32 * K, lb + 2048);
    async_cp16(gp + (size_t)48 * K, lb + 3072);
    gp += 32;                                // advance one K-tile
  };

  auto ldfrag = [&](int slot, bf16x8* fa, bf16x8* fb) {
    const char* base = (const char*)smem + slot * 32768;
#pragma unroll
    for (int mi = 0; mi < 8; ++mi)
      fa[mi] = *(const bf16x8*)(base + aoff + mi * 1024);
#pragma unroll
    for (int ni = 0; ni < 4; ++ni)
      fb[ni] = *(const bf16x8*)(base + boff + ni * 1024);
  };

  auto domfma = [&](const bf16x8* fa, const bf16x8* fb) {
    __builtin_amdgcn_s_setprio(1);
#pragma unroll
    for (int mi = 0; mi < 8; ++mi)
#pragma unroll
      for (int ni = 0; ni < 4; ++ni)
        acc[mi][ni] = __builtin_amdgcn_mfma_f32_16x16x32_bf16(fa[mi], fb[ni], acc[mi][ni], 0, 0, 0);
    __builtin_amdgcn_s_setprio(0);
  };

  bf16x8 fa0[8], fb0[4], fa1[8], fb1[4];

  // prologue: 3 tiles in flight; tiles 0,1 landed before first barrier
  stage(0); stage(1); stage(2);
  asm volatile("s_waitcnt vmcnt(4)\n\ts_barrier" ::: "memory");
  ldfrag(0, fa0, fb0);

  int kt = 0;
  for (; kt + 4 < nkt; kt += 2) {
    // iteration kt (frags in set 0)
    stage((kt + 3) & 3);
    domfma(fa0, fb0);
    ldfrag((kt + 1) & 3, fa1, fb1);
    asm volatile("s_waitcnt vmcnt(4)\n\ts_barrier" ::: "memory");
    // iteration kt+1 (frags in set 1)
    stage((kt + 4) & 3);
    domfma(fa1, fb1);
    ldfrag((kt + 2) & 3, fa0, fb0);
    asm volatile("s_waitcnt vmcnt(4)\n\ts_barrier" ::: "memory");
  }
  // epilogue: iterations nkt-4 .. nkt-1 (kt == nkt-4 here, frags of tile nkt-4 in set 0)
  stage((nkt - 1) & 3);                       // last stage
  domfma(fa0, fb0);
  ldfrag((nkt - 3) & 3, fa1, fb1);
  asm volatile("s_waitcnt vmcnt(4)\n\ts_barrier" ::: "memory");
  domfma(fa1, fb1);
  ldfrag((nkt - 2) & 3, fa0, fb0);
  asm volatile("s_waitcnt vmcnt(0)\n\ts_barrier" ::: "memory");   // tile nkt-1 lands
  domfma(fa0, fb0);
  ldfrag((nkt - 1) & 3, fa1, fb1);            // no more LDS writes: no barrier needed
  domfma(fa1, fb1);

  // ---- epilogue: C mapping col = lane&15, row = quad*4 + reg ----
#pragma unroll
  for (int mi = 0; mi < 8; ++mi) {
    const size_t rowb = m0 + wm * 128 + mi * 16 + quad * 4;
#pragma unroll
    for (int ni = 0; ni < 4; ++ni) {
      const size_t col = n0 + wn * 64 + ni * 16 + frow;
      const float bvs = bias[col];
#pragma unroll
      for (int r = 0; r < 4; ++r) {
        float v = acc[mi][ni][r] + bvs;
        if (EPI == 1) v = fmaxf(v, 0.f);
        const size_t idx = (rowb + r) * (size_t)N + col;
        C[idx] = v;
        if (EPI == 1 && Cbf != nullptr) Cbf[idx] = f2bf(v);
      }
    }
  }
}

// ---------------- BatchNorm: partial column sums -> finalize -> normalize(bf16) ----------------
__global__ __launch_bounds__(256) void bn_accum(const float* __restrict__ h,
                                                float* __restrict__ ps,
                                                float* __restrict__ pq, int N) {
  const int c  = blockIdx.x * 256 + threadIdx.x;
  const int r0 = blockIdx.y * 256;
  const float* p = h + (size_t)r0 * N + c;
  float s = 0.f, q = 0.f;
  for (int r = 0; r < 256; r++) {
    float x = p[(size_t)r * N];
    s += x; q += x * x;
  }
  ps[(size_t)blockIdx.y * N + c] = s;
  pq[(size_t)blockIdx.y * N + c] = q;
}

__global__ __launch_bounds__(256) void bn_final(const float* __restrict__ ps,
                                                const float* __restrict__ pq,
                                                const float* __restrict__ g,
                                                const float* __restrict__ beta,
                                                float* __restrict__ stats,
                                                int N, int nb, float invM) {
  const int c = blockIdx.x * 256 + threadIdx.x;
  float s = 0.f, q = 0.f;
  for (int b = 0; b < nb; b++) { s += ps[(size_t)b * N + c]; q += pq[(size_t)b * N + c]; }
  const float mean = s * invM;
  const float var  = q * invM - mean * mean;
  const float sc   = g[c] * rsqrtf(var + 1e-5f);
  stats[c]     = sc;
  stats[N + c] = beta[c] - mean * sc;
}

__global__ __launch_bounds__(256) void bn_norm(const float* __restrict__ h,
                                               const float* __restrict__ stats,
                                               unsigned short* __restrict__ hb, int N) {
  const size_t i4 = (size_t)blockIdx.x * 256 + threadIdx.x;
  const float4 x = ((const float4*)h)[i4];
  const int c = (int)((i4 * 4) & (size_t)(N - 1));   // N = 2048 (pow2)
  const float4 sc = *(const float4*)(stats + c);
  const float4 tt = *(const float4*)(stats + N + c);
  ushort4 ob;
  ob.x = f2bf(x.x * sc.x + tt.x);
  ob.y = f2bf(x.y * sc.y + tt.y);
  ob.z = f2bf(x.z * sc.z + tt.z);
  ob.w = f2bf(x.w * sc.w + tt.w);
  ((ushort4*)hb)[i4] = ob;
}

// ---------------- launch ----------------
extern "C" void kernel_launch(void* const* d_in, const int* in_sizes, int n_in,
                              void* d_out, int out_size, void* d_ws, size_t ws_size,
                              hipStream_t stream) {
  const float* ft0 = (const float*)d_in[1];
  const float* ft1 = (const float*)d_in[2];
  const float* ft2 = (const float*)d_in[3];
  const float* key = (const float*)d_in[4];
  const float* W1  = (const float*)d_in[5];
  const float* b1  = (const float*)d_in[6];
  const float* g1  = (const float*)d_in[7];
  const float* be1 = (const float*)d_in[8];
  const float* W2  = (const float*)d_in[9];
  const float* b2  = (const float*)d_in[10];
  const float* g2  = (const float*)d_in[11];
  const float* be2 = (const float*)d_in[12];
  const float* W3  = (const float*)d_in[13];
  const float* b3  = (const float*)d_in[14];
  const float* We  = (const float*)d_in[15];
  const float* bE  = (const float*)d_in[16];

  float* out         = (float*)d_out;
  float* out_aligned = out;                                         // [8192,2048]
  float* out_extend  = out + (size_t)8192 * 2048;                   // [8192,6144]
  float* out_ft      = out + (size_t)8192 * 2048 + (size_t)8192 * 6144;  // [8192,6144]

  char* ws = (char*)d_ws;
  unsigned short* ft_bf = (unsigned short*)(ws);                 // 100,663,296 B
  unsigned short* Wt1   = (unsigned short*)(ws + 100663296ull);  //  25,165,824
  unsigned short* Wt2   = (unsigned short*)(ws + 125829120ull);  //   8,388,608
  unsigned short* Wt3   = (unsigned short*)(ws + 134217728ull);  //   8,388,608
  unsigned short* WtE   = (unsigned short*)(ws + 142606336ull);  //  25,165,824
  float*          hf    = (float*)(ws + 167772160ull);           //  67,108,864
  unsigned short* hba   = (unsigned short*)(ws + 234881024ull);  //  33,554,432
  unsigned short* hbb   = (unsigned short*)(ws + 268435456ull);  //  33,554,432
  float*          psum  = (float*)(ws + 301989888ull);           //     262,144
  float*          psq   = (float*)(ws + 302252032ull);           //     262,144
  float*          stats = (float*)(ws + 302514176ull);           //      16,384

  const dim3 blk32(32, 8);
  wconv<<<dim3(2048 / 32, 6144 / 32), blk32, 0, stream>>>(W1, Wt1, 6144, 2048);
  wconv<<<dim3(2048 / 32, 2048 / 32), blk32, 0, stream>>>(W2, Wt2, 2048, 2048);
  wconv<<<dim3(2048 / 32, 2048 / 32), blk32, 0, stream>>>(W3, Wt3, 2048, 2048);
  wconv<<<dim3(6144 / 32, 2048 / 32), blk32, 0, stream>>>(We, WtE, 2048, 6144);

  score_kernel<<<dim3(8192), dim3(256), 0, stream>>>(ft0, ft1, ft2, key, out_ft, ft_bf);

  // layer 1: h = ft_all @ W1 + b1 ; BN
  gemm256<0><<<dim3(8, 32), dim3(512), 0, stream>>>(ft_bf, Wt1, b1, hf,
                                                    (unsigned short*)nullptr, 8192, 2048, 6144);
  bn_accum<<<dim3(8, 32), dim3(256), 0, stream>>>(hf, psum, psq, 2048);
  bn_final<<<dim3(8), dim3(256), 0, stream>>>(psum, psq, g1, be1, stats, 2048, 32, 1.0f / 8192.0f);
  bn_norm<<<dim3(16384), dim3(256), 0, stream>>>(hf, stats, hba, 2048);

  // layer 2: h = h1n @ W2 + b2 ; BN
  gemm256<0><<<dim3(8, 32), dim3(512), 0, stream>>>(hba, Wt2, b2, hf,
                                                    (unsigned short*)nullptr, 8192, 2048, 2048);
  bn_accum<<<dim3(8, 32), dim3(256), 0, stream>>>(hf, psum, psq, 2048);
  bn_final<<<dim3(8), dim3(256), 0, stream>>>(psum, psq, g2, be2, stats, 2048, 32, 1.0f / 8192.0f);
  bn_norm<<<dim3(16384), dim3(256), 0, stream>>>(hf, stats, hba, 2048);

  // layer 3: aligned = relu(h2n @ W3 + b3)  -> fp32 out + bf16 copy
  gemm256<1><<<dim3(8, 32), dim3(512), 0, stream>>>(hba, Wt3, b3, out_aligned, hbb,
                                                    8192, 2048, 2048);
  // extend = relu(aligned @ We + bE)
  gemm256<1><<<dim3(24, 32), dim3(512), 0, stream>>>(hbb, WtE, bE, out_extend,
                                                     (unsigned short*)nullptr, 8192, 6144, 2048);
}